// Round 2
// baseline (747.938 us; speedup 1.0000x reference)
//
#include <hip/hip_runtime.h>

// CrossAttentionPro on MI355X — Round 1: correct f16-MFMA pipeline,
// workspace reduced to ~203 MB by chunking the [B,H,T,T] chained-score
// buffer (4 z-chunks of 32 MB) and deleting the fp32 cval buffer.
// All matmuls NT (A row-major [rows,K], B row-major [cols,K]):
// v stored transposed, catt_y2x computed transposed.
// scale=1/8 folded into q (exact); chained's extra *scale in GEMM epilogue.

typedef _Float16 half_t;
typedef _Float16 half8 __attribute__((ext_vector_type(8)));
typedef float floatx4 __attribute__((ext_vector_type(4)));

constexpr int Bc = 2, Tc = 2048, Mc = 1024, Cc = 512, Hc = 8, Dc = 64;
constexpr int CHUNK_Z = 4;   // z-chunking of the [B*H,T,T] chained buffer

enum { EPI_F16STORE = 0, EPI_QKV = 1, EPI_CVALSTORE = 2, EPI_CVALDIFF = 3, EPI_PROJ = 4 };

struct EpiParams {
  half_t* h0;        // primary f16 dest (q / catt / CH / CV2 / DH)
  half_t* h1;        // k  (QKV) / CV2 source (CVALDIFF)
  half_t* h2;        // v^T (QKV)
  float* f0;         // final fp32 out (PROJ)
  const float* bias;
  float scale;
  int ldc;
  long bstride;
  int seq;
  int zbase;
};

// ---------------------------------------------------------------- GEMM (NT)
// C[r,c] = sum_k A[r,k] * Bt[c,k], f16 in, fp32 MFMA accum.
// Grid: (cols/BN, rows/BM, batch). All dims exactly divisible.
template <int BM, int BN, int WMG, int WNG, int EPI>
__global__ __launch_bounds__(256) void gemm_nt(
    const half_t* __restrict__ A, const half_t* __restrict__ Bt,
    int K, int lda, int ldb, long bsA, long bsB, EpiParams ep)
{
  constexpr int BK = 32, LDP = BK + 8;          // +8 halfs pad vs bank conflicts
  constexpr int WTM = BM / WMG, WTN = BN / WNG; // wave tile
  constexpr int MI = WTM / 16, NI = WTN / 16;
  constexpr int ACH = (BM * BK / 8) / 256;      // 16B chunks per thread (A)
  constexpr int BCH = (BN * BK / 8) / 256;
  __shared__ __align__(16) half_t As[BM * LDP];
  __shared__ __align__(16) half_t Bs[BN * LDP];

  const int tid = threadIdx.x;
  const int lane = tid & 63;
  const int wave = tid >> 6;
  const int wm = wave / WNG, wn = wave % WNG;
  const int z = blockIdx.z;
  const long m0 = (long)blockIdx.y * BM;
  const long n0 = (long)blockIdx.x * BN;
  const half_t* Ab = A + (long)z * bsA;
  const half_t* Bb = Bt + (long)z * bsB;

  floatx4 acc[MI][NI];
#pragma unroll
  for (int mi = 0; mi < MI; ++mi)
#pragma unroll
    for (int ni = 0; ni < NI; ++ni)
      acc[mi][ni] = floatx4{0.f, 0.f, 0.f, 0.f};

  for (int kt = 0; kt < K; kt += BK) {
#pragma unroll
    for (int i = 0; i < ACH; ++i) {
      const int c = tid + i * 256;
      const int row = c >> 2, kc = (c & 3) * 8;
      const uint4 v = *reinterpret_cast<const uint4*>(Ab + (m0 + row) * (long)lda + kt + kc);
      *reinterpret_cast<uint4*>(&As[row * LDP + kc]) = v;
    }
#pragma unroll
    for (int i = 0; i < BCH; ++i) {
      const int c = tid + i * 256;
      const int row = c >> 2, kc = (c & 3) * 8;
      const uint4 v = *reinterpret_cast<const uint4*>(Bb + (n0 + row) * (long)ldb + kt + kc);
      *reinterpret_cast<uint4*>(&Bs[row * LDP + kc]) = v;
    }
    __syncthreads();
    half8 aF[MI], bF[NI];
#pragma unroll
    for (int mi = 0; mi < MI; ++mi)
      aF[mi] = *reinterpret_cast<const half8*>(
          &As[(wm * WTM + mi * 16 + (lane & 15)) * LDP + (lane >> 4) * 8]);
#pragma unroll
    for (int ni = 0; ni < NI; ++ni)
      bF[ni] = *reinterpret_cast<const half8*>(
          &Bs[(wn * WTN + ni * 16 + (lane & 15)) * LDP + (lane >> 4) * 8]);
#pragma unroll
    for (int mi = 0; mi < MI; ++mi)
#pragma unroll
      for (int ni = 0; ni < NI; ++ni)
        acc[mi][ni] = __builtin_amdgcn_mfma_f32_16x16x32_f16(aF[mi], bF[ni], acc[mi][ni], 0, 0, 0);
    __syncthreads();
  }

  // epilogue: C/D layout col=lane&15, row=(lane>>4)*4+reg  [m89-verified]
#pragma unroll
  for (int mi = 0; mi < MI; ++mi) {
#pragma unroll
    for (int ni = 0; ni < NI; ++ni) {
#pragma unroll
      for (int reg = 0; reg < 4; ++reg) {
        const int r = (int)m0 + wm * WTM + mi * 16 + (lane >> 4) * 4 + reg;
        const int c = (int)n0 + wn * WTN + ni * 16 + (lane & 15);
        const float v = acc[mi][ni][reg];
        if constexpr (EPI == EPI_F16STORE) {
          ep.h0[(long)z * ep.bstride + (long)r * ep.ldc + c] = (half_t)(v * ep.scale);
        } else if constexpr (EPI == EPI_QKV) {
          const float val = v + ep.bias[c];
          const int which = c >> 9;     // 0=q 1=k 2=v
          const int cc = c & 511;
          const int h = cc >> 6, d = cc & 63;
          const int b = r / ep.seq, t = r - b * ep.seq;
          const long bh = (long)(b * Hc + h);
          if (which == 0)      ep.h0[(bh * ep.seq + t) * Dc + d] = (half_t)(val * 0.125f);
          else if (which == 1) ep.h1[(bh * ep.seq + t) * Dc + d] = (half_t)val;
          else                 ep.h2[(bh * Dc + d) * ep.seq + t] = (half_t)val;  // v transposed
        } else if constexpr (EPI == EPI_CVALSTORE) {
          const int gz = z + ep.zbase;
          const int b = gz >> 3, h = gz & 7;
          const long idx = ((long)(b * Tc + r)) * Cc + h * Dc + c;
          ep.h0[idx] = (half_t)v;                       // cval_y2x (f16)
        } else if constexpr (EPI == EPI_CVALDIFF) {
          const int b = z >> 3, h = z & 7;
          const long idx = ((long)(b * Tc + r)) * Cc + h * Dc + c;
          ep.h0[idx] = (half_t)(v - (float)ep.h1[idx]); // diff = cval_x2y - cval_y2x
        } else if constexpr (EPI == EPI_PROJ) {
          ep.f0[(long)r * Cc + c] = v + ep.bias[c];
        }
      }
    }
  }
}

// ------------------------------------------------------------- row softmax
__device__ inline float wave_red_max(float v) {
#pragma unroll
  for (int o = 32; o > 0; o >>= 1) v = fmaxf(v, __shfl_xor(v, o));
  return v;
}
__device__ inline float wave_red_sum(float v) {
#pragma unroll
  for (int o = 32; o > 0; o >>= 1) v += __shfl_xor(v, o);
  return v;
}

// In-place softmax over rows of NC f16 elements. Optional int mask row
// (mask==0 -> -inf), mask row index = blockIdx.x % maskT.
template <int NC>
__global__ __launch_bounds__(256) void softmax_rows(half_t* __restrict__ buf,
                                                    const int* __restrict__ mask,
                                                    int maskT)
{
  constexpr int IT = NC / 256;
  const long row = blockIdx.x;
  half_t* p = buf + row * NC;
  const int tid = threadIdx.x, lane = tid & 63, wave = tid >> 6;
  __shared__ float red[4];
  const int* mrow = nullptr;
  if (mask) mrow = mask + (long)((int)(row % maskT)) * NC;
  float v[IT];
  float mx = -3.0e38f;
#pragma unroll
  for (int i = 0; i < IT; ++i) {
    const int c = tid + i * 256;
    float x = (float)p[c];
    if (mrow && mrow[c] == 0) x = -__builtin_inff();
    v[i] = x;
    mx = fmaxf(mx, x);
  }
  mx = wave_red_max(mx);
  if (lane == 0) red[wave] = mx;
  __syncthreads();
  mx = fmaxf(fmaxf(red[0], red[1]), fmaxf(red[2], red[3]));
  __syncthreads();
  float s = 0.f;
#pragma unroll
  for (int i = 0; i < IT; ++i) {
    v[i] = __expf(v[i] - mx);
    s += v[i];
  }
  s = wave_red_sum(s);
  if (lane == 0) red[wave] = s;
  __syncthreads();
  s = red[0] + red[1] + red[2] + red[3];
  const float inv = 1.f / s;
#pragma unroll
  for (int i = 0; i < IT; ++i)
    p[tid + i * 256] = (half_t)(v[i] * inv);   // same indices this thread read
}

// ------------------------------------------------------------- fp32 -> f16
__global__ void f32_to_f16_k(const float* __restrict__ in, half_t* __restrict__ out, int n) {
  const int i = blockIdx.x * 256 + threadIdx.x;
  if (i < n) out[i] = (half_t)in[i];
}

// ------------------------------------------------------------- workspace map
constexpr size_t OFF_XH    = 0;                               // [B*T,C] f16
constexpr size_t OFF_YH    = OFF_XH    + (size_t)Bc*Tc*Cc*2;  // [B*M,C] f16
constexpr size_t OFF_WQ    = OFF_YH    + (size_t)Bc*Mc*Cc*2;  // [3C,C]  f16
constexpr size_t OFF_WP    = OFF_WQ    + (size_t)3*Cc*Cc*2;   // [C,C]   f16
constexpr size_t OFF_QX    = OFF_WP    + (size_t)Cc*Cc*2;     // [B,H,T,D] (scaled)
constexpr size_t OFF_KX    = OFF_QX    + (size_t)Bc*Hc*Tc*Dc*2;
constexpr size_t OFF_VXT   = OFF_KX    + (size_t)Bc*Hc*Tc*Dc*2; // [B,H,D,T]
constexpr size_t OFF_QY    = OFF_VXT   + (size_t)Bc*Hc*Tc*Dc*2; // [B,H,M,D] (scaled)
constexpr size_t OFF_KY    = OFF_QY    + (size_t)Bc*Hc*Mc*Dc*2;
constexpr size_t OFF_VYT   = OFF_KY    + (size_t)Bc*Hc*Mc*Dc*2; // [B,H,D,M]
constexpr size_t OFF_CATT  = OFF_VYT   + (size_t)Bc*Hc*Mc*Dc*2; // [B,H,T,M] f16
constexpr size_t OFF_CATTT = OFF_CATT  + (size_t)Bc*Hc*Tc*Mc*2; // [B,H,T,M] f16 (=catt_y2x^T)
constexpr size_t OFF_CH    = OFF_CATTT + (size_t)Bc*Hc*Tc*Mc*2; // [CHUNK_Z,T,T] f16 (chunked!)
constexpr size_t OFF_CV2   = OFF_CH    + (size_t)CHUNK_Z*Tc*Tc*2; // [B,T,C] f16 cval_y2x
constexpr size_t OFF_DH    = OFF_CV2   + (size_t)Bc*Tc*Cc*2;      // [B,T,C] f16 diff
constexpr size_t WS_TOTAL  = OFF_DH    + (size_t)Bc*Tc*Cc*2;
// total ~203.4 MB

extern "C" void kernel_launch(void* const* d_in, const int* in_sizes, int n_in,
                              void* d_out, int out_size, void* d_ws, size_t ws_size,
                              hipStream_t stream) {
  const float* x      = (const float*)d_in[0];
  const float* y      = (const float*)d_in[1];
  const int*   mask   = (const int*)  d_in[2];
  const float* qkv_w  = (const float*)d_in[3];
  const float* qkv_b  = (const float*)d_in[4];
  const float* proj_w = (const float*)d_in[5];
  const float* proj_b = (const float*)d_in[6];
  float* out = (float*)d_out;
  char* ws = (char*)d_ws;

  half_t* XH    = (half_t*)(ws + OFF_XH);
  half_t* YH    = (half_t*)(ws + OFF_YH);
  half_t* WQ    = (half_t*)(ws + OFF_WQ);
  half_t* WP    = (half_t*)(ws + OFF_WP);
  half_t* QX    = (half_t*)(ws + OFF_QX);
  half_t* KX    = (half_t*)(ws + OFF_KX);
  half_t* VXT   = (half_t*)(ws + OFF_VXT);
  half_t* QY    = (half_t*)(ws + OFF_QY);
  half_t* KY    = (half_t*)(ws + OFF_KY);
  half_t* VYT   = (half_t*)(ws + OFF_VYT);
  half_t* CATT  = (half_t*)(ws + OFF_CATT);
  half_t* CATTT = (half_t*)(ws + OFF_CATTT);
  half_t* CH    = (half_t*)(ws + OFF_CH);
  half_t* CV2   = (half_t*)(ws + OFF_CV2);
  half_t* DH    = (half_t*)(ws + OFF_DH);

  // fp32 -> f16 converts
  f32_to_f16_k<<<(Bc*Tc*Cc + 255) / 256, 256, 0, stream>>>(x, XH, Bc*Tc*Cc);
  f32_to_f16_k<<<(Bc*Mc*Cc + 255) / 256, 256, 0, stream>>>(y, YH, Bc*Mc*Cc);
  f32_to_f16_k<<<(3*Cc*Cc + 255) / 256, 256, 0, stream>>>(qkv_w, WQ, 3*Cc*Cc);
  f32_to_f16_k<<<(Cc*Cc + 255) / 256, 256, 0, stream>>>(proj_w, WP, Cc*Cc);

  // qkv projection (x): [B*T,1536] = XH @ WQ^T + b, scatter into q/k/vT
  {
    EpiParams ep{}; ep.h0 = QX; ep.h1 = KX; ep.h2 = VXT; ep.bias = qkv_b; ep.seq = Tc;
    gemm_nt<128,128,2,2,EPI_QKV><<<dim3(12, 32, 1), 256, 0, stream>>>(
        XH, WQ, Cc, Cc, Cc, 0, 0, ep);
  }
  // qkv projection (y)
  {
    EpiParams ep{}; ep.h0 = QY; ep.h1 = KY; ep.h2 = VYT; ep.bias = qkv_b; ep.seq = Mc;
    gemm_nt<128,128,2,2,EPI_QKV><<<dim3(12, 16, 1), 256, 0, stream>>>(
        YH, WQ, Cc, Cc, Cc, 0, 0, ep);
  }
  // catt_x2y[t,m] = q_x(scaled)[t] . k_y[m]
  {
    EpiParams ep{}; ep.h0 = CATT; ep.scale = 1.f; ep.ldc = Mc; ep.bstride = (long)Tc*Mc;
    gemm_nt<128,128,2,2,EPI_F16STORE><<<dim3(8, 16, Bc*Hc), 256, 0, stream>>>(
        QX, KY, Dc, Dc, Dc, (long)Tc*Dc, (long)Mc*Dc, ep);
  }
  // catt_y2x^T[s,m] = k_x[s] . q_y(scaled)[m]
  {
    EpiParams ep{}; ep.h0 = CATTT; ep.scale = 1.f; ep.ldc = Mc; ep.bstride = (long)Tc*Mc;
    gemm_nt<128,128,2,2,EPI_F16STORE><<<dim3(8, 16, Bc*Hc), 256, 0, stream>>>(
        KX, QY, Dc, Dc, Dc, (long)Tc*Dc, (long)Mc*Dc, ep);
  }

  // Second attention, chunked over z (b*h) to bound the CH buffer:
  // chained[t,s] = 0.125 * sum_m catt[t,m]*cattT[s,m]; masked softmax over s;
  // cval_y2x[t,d] = sum_s P[t,s]*vT_x[d,s] -> CV2 (f16).
  // Only raw CATT/CATTT consumed here, so this runs BEFORE CATT's softmax.
  for (int z0 = 0; z0 < Bc * Hc; z0 += CHUNK_Z) {
    {
      EpiParams ep{}; ep.h0 = CH; ep.scale = 0.125f; ep.ldc = Tc; ep.bstride = (long)Tc*Tc;
      gemm_nt<128,128,2,2,EPI_F16STORE><<<dim3(16, 16, CHUNK_Z), 256, 0, stream>>>(
          CATT + (long)z0*Tc*Mc, CATTT + (long)z0*Tc*Mc,
          Mc, Mc, Mc, (long)Tc*Mc, (long)Tc*Mc, ep);
    }
    softmax_rows<Tc><<<CHUNK_Z*Tc, 256, 0, stream>>>(CH, mask, Tc);
    {
      EpiParams ep{}; ep.h0 = CV2; ep.zbase = z0;
      gemm_nt<64,64,2,2,EPI_CVALSTORE><<<dim3(1, 32, CHUNK_Z), 256, 0, stream>>>(
          CH, VXT + (long)z0*Dc*Tc, Tc, Tc, Tc, (long)Tc*Tc, (long)Dc*Tc, ep);
    }
  }

  // softmax over m (in-place on CATT) — after chained consumed raw scores
  softmax_rows<Mc><<<Bc*Hc*Tc, 256, 0, stream>>>(CATT, nullptr, 1);
  // cval_x2y[t,d] = sum_m P[t,m]*vT_y[d,m]; DH = cval_x2y - CV2
  {
    EpiParams ep{}; ep.h0 = DH; ep.h1 = CV2;
    gemm_nt<64,64,2,2,EPI_CVALDIFF><<<dim3(1, 32, Bc*Hc), 256, 0, stream>>>(
        CATT, VYT, Mc, Mc, Mc, (long)Tc*Mc, (long)Dc*Mc, ep);
  }
  // out = diff @ proj_w^T + proj_b
  {
    EpiParams ep{}; ep.f0 = out; ep.bias = proj_b;
    gemm_nt<128,128,2,2,EPI_PROJ><<<dim3(4, 32, 1), 256, 0, stream>>>(
        DH, WP, Cc, Cc, Cc, 0, 0, ep);
  }
}

// Round 3
// 605.340 us; speedup vs baseline: 1.2356x; 1.2356x over previous
//
#include <hip/hip_runtime.h>

// CrossAttentionPro on MI355X — Round 2:
//  + global_load_lds width-16 async staging (m93->m97 ladder step) with
//    XOR-swizzled chunk assignment (bank-conflict-free reads, no padding)
//  + occupancy fixes for small GEMMs (cval/proj/qkv_y >= 256 blocks)
//  + vectorized softmax (half8/half4 + int4 mask)
// Structure unchanged from R1: all matmuls NT, v stored transposed,
// catt_y2x computed transposed, CH chunked by 4 z to bound workspace.

typedef _Float16 half_t;
typedef _Float16 half8 __attribute__((ext_vector_type(8)));
typedef float floatx4 __attribute__((ext_vector_type(4)));

constexpr int Bc = 2, Tc = 2048, Mc = 1024, Cc = 512, Hc = 8, Dc = 64;
constexpr int CHUNK_Z = 4;   // z-chunking of the [B*H,T,T] chained buffer

enum { EPI_F16STORE = 0, EPI_QKV = 1, EPI_CVALSTORE = 2, EPI_CVALDIFF = 3, EPI_PROJ = 4 };

struct EpiParams {
  half_t* h0;        // primary f16 dest (q / catt / CH / CV2 / DH)
  half_t* h1;        // k  (QKV) / CV2 source (CVALDIFF)
  half_t* h2;        // v^T (QKV)
  float* f0;         // final fp32 out (PROJ)
  const float* bias;
  float scale;
  int ldc;
  long bstride;
  int seq;
  int zbase;
};

// async global->LDS, 16B per lane. HW dest = wave-uniform base + lane*16,
// so the per-lane lds pointer MUST be base + lane*16 (it is: c*16B, c=tid+i*256).
__device__ __forceinline__ void gld_lds16(const half_t* g, half_t* l) {
  __builtin_amdgcn_global_load_lds(
      (const __attribute__((address_space(1))) void*)g,
      (__attribute__((address_space(3))) void*)l, 16, 0, 0);
}

// ---------------------------------------------------------------- GEMM (NT)
// C[r,c] = sum_k A[r,k] * Bt[c,k], f16 in, fp32 MFMA accum.
// LDS tile layout: unpadded [ROWS][32] halfs, but chunk j of row r holds
// global k-chunk (j ^ ((r>>1)&3)) — swizzle makes frag ds_read_b128s 2-way.
template <int BM, int BN, int WMG, int WNG, int EPI>
__global__ __launch_bounds__(256) void gemm_nt(
    const half_t* __restrict__ A, const half_t* __restrict__ Bt,
    int K, int lda, int ldb, long bsA, long bsB, EpiParams ep)
{
  constexpr int BK = 32;
  constexpr int WTM = BM / WMG, WTN = BN / WNG; // wave tile
  constexpr int MI = WTM / 16, NI = WTN / 16;
  constexpr int ACHUNKS = BM * 4;               // 16B chunks per A k-tile
  constexpr int BCHUNKS = BN * 4;
  __shared__ __align__(16) half_t As[BM * BK];
  __shared__ __align__(16) half_t Bs[BN * BK];

  const int tid = threadIdx.x;
  const int lane = tid & 63;
  const int wave = tid >> 6;
  const int wm = wave / WNG, wn = wave % WNG;
  const int z = blockIdx.z;
  const long m0 = (long)blockIdx.y * BM;
  const long n0 = (long)blockIdx.x * BN;
  const half_t* Abase = A + (long)z * bsA + m0 * (long)lda;
  const half_t* Bbase = Bt + (long)z * bsB + n0 * (long)ldb;

  // fragment-read swizzle terms (constant across mi/ni: row bits 1..2 are
  // unchanged by +16*mi since those adds only touch bits >=4)
  const int rA = wm * WTM + (lane & 15);
  const int rB = wn * WTN + (lane & 15);
  const int swA = ((lane >> 4) ^ ((rA >> 1) & 3)) * 8;
  const int swB = ((lane >> 4) ^ ((rB >> 1) & 3)) * 8;

  floatx4 acc[MI][NI];
#pragma unroll
  for (int mi = 0; mi < MI; ++mi)
#pragma unroll
    for (int ni = 0; ni < NI; ++ni)
      acc[mi][ni] = floatx4{0.f, 0.f, 0.f, 0.f};

  for (int kt = 0; kt < K; kt += BK) {
#pragma unroll
    for (int i = 0; i < (ACHUNKS + 255) / 256; ++i) {
      const int c = tid + i * 256;
      if (ACHUNKS % 256 == 0 || c < ACHUNKS) {
        const int row = c >> 2, js = c & 3;
        const int jg = js ^ ((row >> 1) & 3);
        gld_lds16(Abase + (long)row * lda + kt + jg * 8, As + c * 8);
      }
    }
#pragma unroll
    for (int i = 0; i < (BCHUNKS + 255) / 256; ++i) {
      const int c = tid + i * 256;
      if (BCHUNKS % 256 == 0 || c < BCHUNKS) {
        const int row = c >> 2, js = c & 3;
        const int jg = js ^ ((row >> 1) & 3);
        gld_lds16(Bbase + (long)row * ldb + kt + jg * 8, Bs + c * 8);
      }
    }
    __syncthreads();   // compiler emits s_waitcnt vmcnt(0) before s_barrier
    half8 aF[MI], bF[NI];
#pragma unroll
    for (int mi = 0; mi < MI; ++mi)
      aF[mi] = *reinterpret_cast<const half8*>(&As[(rA + mi * 16) * BK + swA]);
#pragma unroll
    for (int ni = 0; ni < NI; ++ni)
      bF[ni] = *reinterpret_cast<const half8*>(&Bs[(rB + ni * 16) * BK + swB]);
#pragma unroll
    for (int mi = 0; mi < MI; ++mi)
#pragma unroll
      for (int ni = 0; ni < NI; ++ni)
        acc[mi][ni] = __builtin_amdgcn_mfma_f32_16x16x32_f16(aF[mi], bF[ni], acc[mi][ni], 0, 0, 0);
    __syncthreads();
  }

  // epilogue: C/D layout col=lane&15, row=(lane>>4)*4+reg  [m89-verified]
#pragma unroll
  for (int mi = 0; mi < MI; ++mi) {
#pragma unroll
    for (int ni = 0; ni < NI; ++ni) {
#pragma unroll
      for (int reg = 0; reg < 4; ++reg) {
        const int r = (int)m0 + wm * WTM + mi * 16 + (lane >> 4) * 4 + reg;
        const int c = (int)n0 + wn * WTN + ni * 16 + (lane & 15);
        const float v = acc[mi][ni][reg];
        if constexpr (EPI == EPI_F16STORE) {
          ep.h0[(long)z * ep.bstride + (long)r * ep.ldc + c] = (half_t)(v * ep.scale);
        } else if constexpr (EPI == EPI_QKV) {
          const float val = v + ep.bias[c];
          const int which = c >> 9;     // 0=q 1=k 2=v
          const int cc = c & 511;
          const int h = cc >> 6, d = cc & 63;
          const int b = r / ep.seq, t = r - b * ep.seq;
          const long bh = (long)(b * Hc + h);
          if (which == 0)      ep.h0[(bh * ep.seq + t) * Dc + d] = (half_t)(val * 0.125f);
          else if (which == 1) ep.h1[(bh * ep.seq + t) * Dc + d] = (half_t)val;
          else                 ep.h2[(bh * Dc + d) * ep.seq + t] = (half_t)val;  // v transposed
        } else if constexpr (EPI == EPI_CVALSTORE) {
          const int gz = z + ep.zbase;
          const int b = gz >> 3, h = gz & 7;
          const long idx = ((long)(b * Tc + r)) * Cc + h * Dc + c;
          ep.h0[idx] = (half_t)v;                       // cval_y2x (f16)
        } else if constexpr (EPI == EPI_CVALDIFF) {
          const int b = z >> 3, h = z & 7;
          const long idx = ((long)(b * Tc + r)) * Cc + h * Dc + c;
          ep.h0[idx] = (half_t)(v - (float)ep.h1[idx]); // diff = cval_x2y - cval_y2x
        } else if constexpr (EPI == EPI_PROJ) {
          ep.f0[(long)r * Cc + c] = v + ep.bias[c];
        }
      }
    }
  }
}

// ------------------------------------------------------------- row softmax
__device__ inline float wave_red_max(float v) {
#pragma unroll
  for (int o = 32; o > 0; o >>= 1) v = fmaxf(v, __shfl_xor(v, o));
  return v;
}
__device__ inline float wave_red_sum(float v) {
#pragma unroll
  for (int o = 32; o > 0; o >>= 1) v += __shfl_xor(v, o);
  return v;
}

// In-place softmax over rows of NC f16 elements, vectorized (contiguous
// VEC=NC/256 halfs per thread). Optional int mask row (mask==0 -> -inf),
// mask row index = blockIdx.x % maskT.
template <int NC>
__global__ __launch_bounds__(256) void softmax_rows(half_t* __restrict__ buf,
                                                    const int* __restrict__ mask,
                                                    int maskT)
{
  constexpr int VEC = NC / 256;
  typedef _Float16 hvec __attribute__((ext_vector_type(VEC)));
  const long row = blockIdx.x;
  const int tid = threadIdx.x, lane = tid & 63, wave = tid >> 6;
  half_t* p = buf + row * NC + tid * VEC;
  __shared__ float red[4];

  float v[VEC];
  hvec hv = *reinterpret_cast<const hvec*>(p);
#pragma unroll
  for (int i = 0; i < VEC; ++i) v[i] = (float)hv[i];
  if (mask) {
    const int4* m4 = reinterpret_cast<const int4*>(
        mask + (long)((int)(row % maskT)) * NC + tid * VEC);
#pragma unroll
    for (int q = 0; q < VEC / 4; ++q) {
      const int4 mm = m4[q];
      if (mm.x == 0) v[q * 4 + 0] = -__builtin_inff();
      if (mm.y == 0) v[q * 4 + 1] = -__builtin_inff();
      if (mm.z == 0) v[q * 4 + 2] = -__builtin_inff();
      if (mm.w == 0) v[q * 4 + 3] = -__builtin_inff();
    }
  }
  float mx = -3.0e38f;
#pragma unroll
  for (int i = 0; i < VEC; ++i) mx = fmaxf(mx, v[i]);
  mx = wave_red_max(mx);
  if (lane == 0) red[wave] = mx;
  __syncthreads();
  mx = fmaxf(fmaxf(red[0], red[1]), fmaxf(red[2], red[3]));
  __syncthreads();
  float s = 0.f;
#pragma unroll
  for (int i = 0; i < VEC; ++i) {
    v[i] = __expf(v[i] - mx);
    s += v[i];
  }
  s = wave_red_sum(s);
  if (lane == 0) red[wave] = s;
  __syncthreads();
  s = red[0] + red[1] + red[2] + red[3];
  const float inv = 1.f / s;
  hvec res;
#pragma unroll
  for (int i = 0; i < VEC; ++i) res[i] = (half_t)(v[i] * inv);
  *reinterpret_cast<hvec*>(p) = res;
}

// ------------------------------------------------------------- fp32 -> f16
typedef _Float16 half4v __attribute__((ext_vector_type(4)));
__global__ void f32_to_f16_k(const float* __restrict__ in, half_t* __restrict__ out, int n4) {
  const int i = blockIdx.x * 256 + threadIdx.x;
  if (i < n4) {
    const float4 f = reinterpret_cast<const float4*>(in)[i];
    half4v h; h[0] = (half_t)f.x; h[1] = (half_t)f.y; h[2] = (half_t)f.z; h[3] = (half_t)f.w;
    reinterpret_cast<half4v*>(out)[i] = h;
  }
}

// ------------------------------------------------------------- workspace map
constexpr size_t OFF_XH    = 0;                               // [B*T,C] f16
constexpr size_t OFF_YH    = OFF_XH    + (size_t)Bc*Tc*Cc*2;  // [B*M,C] f16
constexpr size_t OFF_WQ    = OFF_YH    + (size_t)Bc*Mc*Cc*2;  // [3C,C]  f16
constexpr size_t OFF_WP    = OFF_WQ    + (size_t)3*Cc*Cc*2;   // [C,C]   f16
constexpr size_t OFF_QX    = OFF_WP    + (size_t)Cc*Cc*2;     // [B,H,T,D] (scaled)
constexpr size_t OFF_KX    = OFF_QX    + (size_t)Bc*Hc*Tc*Dc*2;
constexpr size_t OFF_VXT   = OFF_KX    + (size_t)Bc*Hc*Tc*Dc*2; // [B,H,D,T]
constexpr size_t OFF_QY    = OFF_VXT   + (size_t)Bc*Hc*Tc*Dc*2; // [B,H,M,D] (scaled)
constexpr size_t OFF_KY    = OFF_QY    + (size_t)Bc*Hc*Mc*Dc*2;
constexpr size_t OFF_VYT   = OFF_KY    + (size_t)Bc*Hc*Mc*Dc*2; // [B,H,D,M]
constexpr size_t OFF_CATT  = OFF_VYT   + (size_t)Bc*Hc*Mc*Dc*2; // [B,H,T,M] f16
constexpr size_t OFF_CATTT = OFF_CATT  + (size_t)Bc*Hc*Tc*Mc*2; // [B,H,T,M] f16 (=catt_y2x^T)
constexpr size_t OFF_CH    = OFF_CATTT + (size_t)Bc*Hc*Tc*Mc*2; // [CHUNK_Z,T,T] f16 (chunked)
constexpr size_t OFF_CV2   = OFF_CH    + (size_t)CHUNK_Z*Tc*Tc*2; // [B,T,C] f16 cval_y2x
constexpr size_t OFF_DH    = OFF_CV2   + (size_t)Bc*Tc*Cc*2;      // [B,T,C] f16 diff
// total ~203.4 MB

extern "C" void kernel_launch(void* const* d_in, const int* in_sizes, int n_in,
                              void* d_out, int out_size, void* d_ws, size_t ws_size,
                              hipStream_t stream) {
  const float* x      = (const float*)d_in[0];
  const float* y      = (const float*)d_in[1];
  const int*   mask   = (const int*)  d_in[2];
  const float* qkv_b  = (const float*)d_in[4];
  const float* proj_b = (const float*)d_in[6];
  float* out = (float*)d_out;
  char* ws = (char*)d_ws;

  half_t* XH    = (half_t*)(ws + OFF_XH);
  half_t* YH    = (half_t*)(ws + OFF_YH);
  half_t* WQ    = (half_t*)(ws + OFF_WQ);
  half_t* WP    = (half_t*)(ws + OFF_WP);
  half_t* QX    = (half_t*)(ws + OFF_QX);
  half_t* KX    = (half_t*)(ws + OFF_KX);
  half_t* VXT   = (half_t*)(ws + OFF_VXT);
  half_t* QY    = (half_t*)(ws + OFF_QY);
  half_t* KY    = (half_t*)(ws + OFF_KY);
  half_t* VYT   = (half_t*)(ws + OFF_VYT);
  half_t* CATT  = (half_t*)(ws + OFF_CATT);
  half_t* CATTT = (half_t*)(ws + OFF_CATTT);
  half_t* CH    = (half_t*)(ws + OFF_CH);
  half_t* CV2   = (half_t*)(ws + OFF_CV2);
  half_t* DH    = (half_t*)(ws + OFF_DH);

  // fp32 -> f16 converts (float4 / half4)
  f32_to_f16_k<<<(Bc*Tc*Cc/4 + 255) / 256, 256, 0, stream>>>(x, XH, Bc*Tc*Cc/4);
  f32_to_f16_k<<<(Bc*Mc*Cc/4 + 255) / 256, 256, 0, stream>>>(y, YH, Bc*Mc*Cc/4);
  f32_to_f16_k<<<(3*Cc*Cc/4 + 255) / 256, 256, 0, stream>>>((const float*)d_in[3], WQ, 3*Cc*Cc/4);
  f32_to_f16_k<<<(Cc*Cc/4 + 255) / 256, 256, 0, stream>>>((const float*)d_in[5], WP, Cc*Cc/4);

  // qkv projection (x): [B*T,1536] = XH @ WQ^T + b, scatter into q/k/vT
  {
    EpiParams ep{}; ep.h0 = QX; ep.h1 = KX; ep.h2 = VXT; ep.bias = qkv_b; ep.seq = Tc;
    gemm_nt<128,128,2,2,EPI_QKV><<<dim3(12, 32, 1), 256, 0, stream>>>(
        XH, WQ, Cc, Cc, Cc, 0, 0, ep);
  }
  // qkv projection (y) — BM=64 for 384 blocks
  {
    EpiParams ep{}; ep.h0 = QY; ep.h1 = KY; ep.h2 = VYT; ep.bias = qkv_b; ep.seq = Mc;
    gemm_nt<64,128,2,2,EPI_QKV><<<dim3(12, 32, 1), 256, 0, stream>>>(
        YH, WQ, Cc, Cc, Cc, 0, 0, ep);
  }
  // catt_x2y[t,m] = q_x(scaled)[t] . k_y[m]
  {
    EpiParams ep{}; ep.h0 = CATT; ep.scale = 1.f; ep.ldc = Mc; ep.bstride = (long)Tc*Mc;
    gemm_nt<128,128,2,2,EPI_F16STORE><<<dim3(8, 16, Bc*Hc), 256, 0, stream>>>(
        QX, KY, Dc, Dc, Dc, (long)Tc*Dc, (long)Mc*Dc, ep);
  }
  // catt_y2x^T[s,m] = k_x[s] . q_y(scaled)[m]
  {
    EpiParams ep{}; ep.h0 = CATTT; ep.scale = 1.f; ep.ldc = Mc; ep.bstride = (long)Tc*Mc;
    gemm_nt<128,128,2,2,EPI_F16STORE><<<dim3(8, 16, Bc*Hc), 256, 0, stream>>>(
        KX, QY, Dc, Dc, Dc, (long)Tc*Dc, (long)Mc*Dc, ep);
  }

  // Second attention, chunked over z (b*h) to bound the CH buffer:
  // chained[t,s] = 0.125 * sum_m catt[t,m]*cattT[s,m]; masked softmax over s;
  // cval_y2x[t,d] = sum_s P[t,s]*vT_x[d,s] -> CV2 (f16).
  for (int z0 = 0; z0 < Bc * Hc; z0 += CHUNK_Z) {
    {
      EpiParams ep{}; ep.h0 = CH; ep.scale = 0.125f; ep.ldc = Tc; ep.bstride = (long)Tc*Tc;
      gemm_nt<128,128,2,2,EPI_F16STORE><<<dim3(16, 16, CHUNK_Z), 256, 0, stream>>>(
          CATT + (long)z0*Tc*Mc, CATTT + (long)z0*Tc*Mc,
          Mc, Mc, Mc, (long)Tc*Mc, (long)Tc*Mc, ep);
    }
    softmax_rows<Tc><<<CHUNK_Z*Tc, 256, 0, stream>>>(CH, mask, Tc);
    {
      EpiParams ep{}; ep.h0 = CV2; ep.zbase = z0;
      gemm_nt<32,64,2,2,EPI_CVALSTORE><<<dim3(1, 64, CHUNK_Z), 256, 0, stream>>>(
          CH, VXT + (long)z0*Dc*Tc, Tc, Tc, Tc, (long)Tc*Tc, (long)Dc*Tc, ep);
    }
  }

  // softmax over m (in-place on CATT) — after chained consumed raw scores
  softmax_rows<Mc><<<Bc*Hc*Tc, 256, 0, stream>>>(CATT, nullptr, 1);
  // cval_x2y[t,d] = sum_m P[t,m]*vT_y[d,m]; DH = cval_x2y - CV2
  {
    EpiParams ep{}; ep.h0 = DH; ep.h1 = CV2;
    gemm_nt<32,64,2,2,EPI_CVALDIFF><<<dim3(1, 64, Bc*Hc), 256, 0, stream>>>(
        CATT, VYT, Mc, Mc, Mc, (long)Tc*Mc, (long)Dc*Mc, ep);
  }
  // out = diff @ proj_w^T + proj_b  (BN=64 for 256 blocks)
  {
    EpiParams ep{}; ep.f0 = out; ep.bias = proj_b;
    gemm_nt<128,64,2,2,EPI_PROJ><<<dim3(8, 32, 1), 256, 0, stream>>>(
        DH, WP, Cc, Cc, Cc, 0, 0, ep);
  }
}